// Round 7
// baseline (460.980 us; speedup 1.0000x reference)
//
#include <hip/hip_runtime.h>
#include <hip/hip_bf16.h>

#define VOCAB 32000
#define EMBED 1024
#define SEQ 256
#define BATCH 8
#define ROWS (SEQ * BATCH) /* 2048 */

#define BM 256
#define BN 256
#define BK 64
#define NT (EMBED / BK) /* 16 K-tiles */
#define LDS_TOTAL 163840 /* 128 KiB dbuf + 32 KiB dedicated epilogue T */

typedef short short8 __attribute__((ext_vector_type(8)));
typedef float f32x4 __attribute__((ext_vector_type(4)));

__device__ __forceinline__ unsigned short f2bf(float f) {
    __hip_bfloat16 h = __float2bfloat16(f);
    return *reinterpret_cast<unsigned short*>(&h);
}

#define GLOAD_LDS16(gsrc, ldst)                                                        \
    __builtin_amdgcn_global_load_lds((const __attribute__((address_space(1))) void*)(gsrc), \
                                     (__attribute__((address_space(3))) void*)(ldst), 16, 0, 0)

// ---------------- fused pre-pass: transpose (blocks 0..7999) + embed (blocks 8000..10047) ----------------
__global__ __launch_bounds__(256) void prep_k(const int* __restrict__ toks,
                                              const float* __restrict__ W1,
                                              const float* __restrict__ b1,
                                              const float* __restrict__ W2,
                                              unsigned short* __restrict__ h,
                                              unsigned short* __restrict__ W2t) {
    __shared__ float tile[64][65];
    int bid = blockIdx.x;
    int t = threadIdx.x;
    if (bid < 8000) {
        int n0 = (bid % 500) * 64;
        int k0 = (bid / 500) * 64;
        int tx = t & 15, ty = t >> 4;
#pragma unroll
        for (int p = 0; p < 4; ++p) {
            int k = ty + p * 16;
            float4 v = *(const float4*)(W2 + (size_t)(k0 + k) * VOCAB + n0 + tx * 4);
            tile[k][tx * 4 + 0] = v.x; tile[k][tx * 4 + 1] = v.y;
            tile[k][tx * 4 + 2] = v.z; tile[k][tx * 4 + 3] = v.w;
        }
        __syncthreads();
        int kx = t & 15, ny = t >> 4;
#pragma unroll
        for (int p = 0; p < 4; ++p) {
            int n = ny + p * 16;
            int k = kx * 4;
            union { unsigned short u[4]; uint2 v; } o;
            o.u[0] = f2bf(tile[k + 0][n]); o.u[1] = f2bf(tile[k + 1][n]);
            o.u[2] = f2bf(tile[k + 2][n]); o.u[3] = f2bf(tile[k + 3][n]);
            *(uint2*)(W2t + (size_t)(n0 + n) * EMBED + k0 + k) = o.v;
        }
    } else {
        int r = bid - 8000;
        int s = r >> 3, b = r & 7;
        int t0 = (s >= 3) ? toks[(s - 3) * BATCH + b] : 0;
        int t1 = (s >= 2) ? toks[(s - 2) * BATCH + b] : 0;
        int t2 = (s >= 1) ? toks[(s - 1) * BATCH + b] : 0;
        int e = t * 4;
        float4 vb = *(const float4*)(b1 + e);
        float4 v0 = *(const float4*)(W1 + ((size_t)0 * VOCAB + t0) * EMBED + e);
        float4 v1 = *(const float4*)(W1 + ((size_t)1 * VOCAB + t1) * EMBED + e);
        float4 v2 = *(const float4*)(W1 + ((size_t)2 * VOCAB + t2) * EMBED + e);
        float x0 = fmaxf(vb.x + v0.x + v1.x + v2.x, 0.0f);
        float x1 = fmaxf(vb.y + v0.y + v1.y + v2.y, 0.0f);
        float x2 = fmaxf(vb.z + v0.z + v1.z + v2.z, 0.0f);
        float x3 = fmaxf(vb.w + v0.w + v1.w + v2.w, 0.0f);
        union { unsigned short u[4]; uint2 v; } o;
        o.u[0] = f2bf(x0); o.u[1] = f2bf(x1); o.u[2] = f2bf(x2); o.u[3] = f2bf(x3);
        *(uint2*)(h + (size_t)r * EMBED + e) = o.v;
    }
}

// ---------------- persistent 256x256 8-phase bf16 MFMA GEMM: 2 m-tiles per block ----------------
// LDS 160 KiB: [0,64K) A dbuf, [64K,128K) B dbuf, [128K,160K) DEDICATED epilogue transpose T.
// (r6's NaN: T aliased buf1.A which the boundary now prestages -> clobber. Dedicated T fixes it.)
// Epilogue: plain (write-allocating) full-line stores via LDS transpose -> no RMW, L2-rate ack.
// Boundary: wrap prefetch leaves buf0.B=B(t0), buf1.B=B(t1); prestage A(m1,t0)->buf0.A AND
// A(m1,t1)->buf1.A BEFORE the 32-store epilogue; vmcnt(32) retires all loads w/o store drain;
// kloop(m1) it0 skips ph1-2 staging and ph4 vmcnt -> first store-touching wait is it0-ph8,
// 8 compute phases after store issue.
__global__ __launch_bounds__(512, 2) void gemm8_k(const unsigned short* __restrict__ A,
                                                  const unsigned short* __restrict__ B,
                                                  const float* __restrict__ b2,
                                                  float* __restrict__ out) {
    extern __shared__ char lds[];
    char* Al = lds;
    char* Bl = lds + 65536;

    // bijective XCD swizzle for 500 blocks (m204): q=62, r=4
    int wg = blockIdx.x;
    int xcd = wg & 7, idx = wg >> 3;
    int wgid = (xcd < 4 ? xcd * 63 : 4 * 63 + (xcd - 4) * 62) + idx;
    int mg = wgid & 3;            // m fast: same-stripe blocks adjacent
    int n0 = (wgid >> 2) * BN;
    int m0 = mg * 512;

    int tid = threadIdx.x;
    int w = tid >> 6, lane = tid & 63;
    int wm = w >> 2, wn = w & 3;
    int ksw = ((lane & 7) ^ ((lane >> 3) & 7)) * 8;

    f32x4 acc[8][4] = {};
    short8 af[2][2], bfr[4][2];

    auto stage = [&](const unsigned short* __restrict__ g, int grow0, char* ldsbase, int t) {
#pragma unroll
        for (int j = 0; j < 2; ++j) {
            int c = j * 8 + w;
            int row = c * 8 + (lane >> 3);
            const unsigned short* src = g + (size_t)(grow0 + row) * EMBED + t * BK + ksw;
            GLOAD_LDS16(src, ldsbase + c * 1024);
        }
    };
    auto stA = [&](int buf, int hh, int t, int mbase) { stage(A, mbase + hh * 128, Al + buf * 32768 + hh * 16384, t); };
    auto stB = [&](int buf, int hh, int t) { stage(B, n0 + hh * 128, Bl + buf * 32768 + hh * 16384, t); };

    auto ldA = [&](int buf, int qq) {
#pragma unroll
        for (int i = 0; i < 2; ++i)
#pragma unroll
            for (int kk = 0; kk < 2; ++kk) {
                int row = wm * 128 + (qq * 2 + i) * 16 + (lane & 15);
                int cb = ((lane >> 4) * 16 + kk * 64) ^ ((lane & 7) << 4);
                af[i][kk] = *(const short8*)(Al + buf * 32768 + row * 128 + cb);
            }
    };
    auto ldB = [&](int buf) {
#pragma unroll
        for (int n = 0; n < 4; ++n)
#pragma unroll
            for (int kk = 0; kk < 2; ++kk) {
                int row = wn * 64 + n * 16 + (lane & 15);
                int cb = ((lane >> 4) * 16 + kk * 64) ^ ((lane & 7) << 4);
                bfr[n][kk] = *(const short8*)(Bl + buf * 32768 + row * 128 + cb);
            }
    };

#define MFMA_Q(q)                                                                             \
    __builtin_amdgcn_s_setprio(1);                                                            \
    _Pragma("unroll") for (int i = 0; i < 2; ++i)                                             \
        _Pragma("unroll") for (int n = 0; n < 4; ++n)                                         \
            _Pragma("unroll") for (int kk = 0; kk < 2; ++kk)                                  \
                acc[(q)*2 + i][n] = __builtin_amdgcn_mfma_f32_16x16x32_bf16(                  \
                    af[i][kk], bfr[n][kk], acc[(q)*2 + i][n], 0, 0, 0);                       \
    __builtin_amdgcn_s_setprio(0);

#define PH(ldbuf, q, DO_LDB, STAGE_STMT, WAITV)                                               \
    ldA(ldbuf, q);                                                                            \
    if (DO_LDB) ldB(ldbuf);                                                                   \
    STAGE_STMT;                                                                               \
    if (DO_LDB) asm volatile("s_waitcnt lgkmcnt(8)");                                         \
    if (WAITV) asm volatile("s_waitcnt vmcnt(4)");                                            \
    __builtin_amdgcn_s_barrier();                                                             \
    asm volatile("s_waitcnt lgkmcnt(0)");                                                     \
    MFMA_Q(q);                                                                                \
    __builtin_amdgcn_s_barrier();

    // 8-phase K-loop; wrap prefetches at it=7 restore prologue B-state for the next m-tile.
    // skipFirstA: tiles t0 AND t1 fully pre-staged -> it0 skips ph1-2 stages and ph4 vmcnt.
    auto kloop = [&](int mcur, bool skipFirstA) {
        for (int it = 0; it < NT / 2; ++it) {
            int t1 = (it * 2 + 1) & (NT - 1);
            int t2 = (it * 2 + 2) & (NT - 1);
            int t3 = (it * 2 + 3) & (NT - 1);
            if (it == 0 && skipFirstA) {
                PH(0, 0, true,  (void)0,             false)
                PH(0, 1, false, (void)0,             false)
                PH(0, 2, false, stB(0, 0, t2),       false)
                PH(0, 3, false, stB(0, 1, t2),       false)  // no vmcnt: t1 pre-landed
                PH(1, 0, true,  stA(0, 0, t2, mcur), false)
                PH(1, 1, false, stA(0, 1, t2, mcur), false)
                PH(1, 2, false, stB(1, 0, t3),       false)
                PH(1, 3, false, stB(1, 1, t3),       true)
            } else {
                PH(0, 0, true,  stA(1, 0, t1, mcur), false)
                PH(0, 1, false, stA(1, 1, t1, mcur), false)
                PH(0, 2, false, stB(0, 0, t2),       false)
                PH(0, 3, false, stB(0, 1, t2),       true)
                PH(1, 0, true,  stA(0, 0, t2, mcur), false)
                PH(1, 1, false, stA(0, 1, t2, mcur), false)
                PH(1, 2, false, stB(1, 0, t3),       false)
                PH(1, 3, false, stB(1, 1, t3),       true)
            }
        }
    };

    // ---- full-line epilogue via DEDICATED LDS transpose region (32 KB), plain stores ----
    int colq = lane & 15;
    int rowq4 = (lane >> 4) * 4;
    auto epi = [&](int mbase) {
        char* T = lds + 131072;   // dedicated: never aliases A/B buffers
        float bias[4];
#pragma unroll
        for (int nf = 0; nf < 4; ++nf) bias[nf] = b2[n0 + wn * 64 + nf * 16 + colq];
#pragma unroll
        for (int p = 0; p < 8; ++p) {
            __builtin_amdgcn_s_barrier();   // prior pass readback done before overwrite
            if (wm == (p >> 2)) {
#pragma unroll
                for (int mi = 0; mi < 2; ++mi) {
                    int mf = (p & 3) * 2 + mi;
                    int rl = mi * 16 + rowq4;
#pragma unroll
                    for (int nf = 0; nf < 4; ++nf) {
                        int c = wn * 64 + nf * 16 + colq;
#pragma unroll
                        for (int q = 0; q < 4; ++q)
                            *(float*)(T + (rl + q) * 1024 + c * 4) = acc[mf][nf][q] + bias[nf];
                    }
                }
            }
            __builtin_amdgcn_s_barrier();
#pragma unroll
            for (int rr = 0; rr < 4; ++rr) {
                int rl = w * 4 + rr;
                f32x4 v = *(const f32x4*)(T + rl * 1024 + lane * 16);
                int grow = mbase + p * 32 + rl;
                *(f32x4*)(out + (size_t)grow * VOCAB + n0 + lane * 4) = v;
            }
        }
    };

    // ---- prologue (m-tile 0) ----
    stA(0, 0, 0, m0); stA(0, 1, 0, m0); stB(0, 0, 0); stB(0, 1, 0);
    stB(1, 0, 1); stB(1, 1, 1);
    asm volatile("s_waitcnt vmcnt(4)");
    __builtin_amdgcn_s_barrier();

    kloop(m0, false);

    // ---- boundary: prestage the new m-slab's A for t0->buf0.A AND t1->buf1.A (8 loads)
    // BEFORE the epilogue stores (WAR-safe: all loop ds_reads of both A buffers completed
    // before the trailing barriers). FIFO at vmcnt(32): 4 wrapB + 8 prestage + 4 bias + 32
    // stores = 48 outstanding -> retires exactly the 16 loads, zero store drain.
    int m1 = m0 + 256;
    stA(0, 0, 0, m1); stA(0, 1, 0, m1);
    stA(1, 0, 1, m1); stA(1, 1, 1, m1);
    asm volatile("" ::: "memory");   // keep prestage issue ahead of epilogue vmem
    epi(m0);
    asm volatile("s_waitcnt vmcnt(32)" ::: "memory");
    __builtin_amdgcn_s_barrier();

#pragma unroll
    for (int mf = 0; mf < 8; ++mf)
#pragma unroll
        for (int nf = 0; nf < 4; ++nf)
            acc[mf][nf] = f32x4{0.f, 0.f, 0.f, 0.f};

    kloop(m1, true);
    epi(m1);
#undef PH
#undef MFMA_Q
}

// ---------------- fallback 128^2 2-phase GEMM (if 160 KiB dyn LDS unavailable) ----------------
__global__ __launch_bounds__(256) void gemm_k(const unsigned short* __restrict__ h,
                                              const unsigned short* __restrict__ W2t,
                                              const float* __restrict__ b2,
                                              float* __restrict__ out) {
    __shared__ unsigned short Alds[128 * 64];
    __shared__ unsigned short Blds[128 * 64];
    int m0 = blockIdx.x * 128;
    int n0 = blockIdx.y * 128;
    int tid = threadIdx.x;
    int wave = tid >> 6, lane = tid & 63;
    int wr = (wave >> 1) * 64;
    int wc = (wave & 1) * 64;
    int lrow = lane & 15;
    int khalf = (lane >> 4) * 8;
    f32x4 acc[4][4] = {};
    for (int kt = 0; kt < EMBED; kt += 64) {
#pragma unroll
        for (int i = 0; i < 4; ++i) {
            int base = (wave * 4 + i) * 1024;
            int lin = base + lane * 16;
            int row = lin >> 7;
            int colu = (lin & 127) >> 1;
            GLOAD_LDS16(h + (size_t)(m0 + row) * EMBED + kt + colu, (char*)Alds + base);
            GLOAD_LDS16(W2t + (size_t)(n0 + row) * EMBED + kt + colu, (char*)Blds + base);
        }
        __syncthreads();
#pragma unroll
        for (int kc = 0; kc < 2; ++kc) {
            short8 af[4], bf[4];
#pragma unroll
            for (int m = 0; m < 4; ++m)
                af[m] = *(const short8*)(Alds + (wr + m * 16 + lrow) * 64 + kc * 32 + khalf);
#pragma unroll
            for (int n = 0; n < 4; ++n)
                bf[n] = *(const short8*)(Blds + (wc + n * 16 + lrow) * 64 + kc * 32 + khalf);
#pragma unroll
            for (int m = 0; m < 4; ++m)
#pragma unroll
                for (int n = 0; n < 4; ++n)
                    acc[m][n] = __builtin_amdgcn_mfma_f32_16x16x32_bf16(af[m], bf[n], acc[m][n], 0, 0, 0);
        }
        __syncthreads();
    }
    int colq = lane & 15;
    int rowq = (lane >> 4) * 4;
#pragma unroll
    for (int m = 0; m < 4; ++m)
#pragma unroll
        for (int n = 0; n < 4; ++n) {
            int col = n0 + wc + n * 16 + colq;
            float bias = b2[col];
#pragma unroll
            for (int q = 0; q < 4; ++q)
                out[(size_t)(m0 + wr + m * 16 + rowq + q) * VOCAB + col] = acc[m][n][q] + bias;
        }
}

// ---------------- fallback (ws too small): correct fp32 path ----------------
__global__ __launch_bounds__(256) void naive_k(const int* __restrict__ toks,
                                               const float* __restrict__ W1,
                                               const float* __restrict__ b1,
                                               const float* __restrict__ W2,
                                               const float* __restrict__ b2,
                                               float* __restrict__ out) {
    __shared__ float hs[8][1024];
    int r0 = blockIdx.x * 8;
    int e = threadIdx.x * 4;
    for (int rr = 0; rr < 8; ++rr) {
        int r = r0 + rr, s = r >> 3, b = r & 7;
        int t0 = (s >= 3) ? toks[(s - 3) * BATCH + b] : 0;
        int t1 = (s >= 2) ? toks[(s - 2) * BATCH + b] : 0;
        int t2 = (s >= 1) ? toks[(s - 1) * BATCH + b] : 0;
        float4 vb = *(const float4*)(b1 + e);
        float4 v0 = *(const float4*)(W1 + ((size_t)t0) * EMBED + e);
        float4 v1 = *(const float4*)(W1 + ((size_t)VOCAB + t1) * EMBED + e);
        float4 v2 = *(const float4*)(W1 + ((size_t)2 * VOCAB + t2) * EMBED + e);
        hs[rr][e + 0] = fmaxf(vb.x + v0.x + v1.x + v2.x, 0.0f);
        hs[rr][e + 1] = fmaxf(vb.y + v0.y + v1.y + v2.y, 0.0f);
        hs[rr][e + 2] = fmaxf(vb.z + v0.z + v1.z + v2.z, 0.0f);
        hs[rr][e + 3] = fmaxf(vb.w + v0.w + v1.w + v2.w, 0.0f);
    }
    __syncthreads();
    for (int v = threadIdx.x; v < VOCAB; v += 256) {
        float acc[8];
#pragma unroll
        for (int i = 0; i < 8; ++i) acc[i] = b2[v];
        for (int ee = 0; ee < EMBED; ++ee) {
            float wv = W2[(size_t)ee * VOCAB + v];
#pragma unroll
            for (int i = 0; i < 8; ++i) acc[i] += hs[i][ee] * wv;
        }
#pragma unroll
        for (int i = 0; i < 8; ++i) out[(size_t)(r0 + i) * VOCAB + v] = acc[i];
    }
}

extern "C" void kernel_launch(void* const* d_in, const int* in_sizes, int n_in,
                              void* d_out, int out_size, void* d_ws, size_t ws_size,
                              hipStream_t stream) {
    const int* toks = (const int*)d_in[0];
    const float* W1 = (const float*)d_in[1];
    const float* b1 = (const float*)d_in[2];
    const float* W2 = (const float*)d_in[3];
    const float* b2 = (const float*)d_in[4];
    float* out = (float*)d_out;

    const size_t h_bytes = (size_t)ROWS * EMBED * 2;
    const size_t w2t_bytes = (size_t)VOCAB * EMBED * 2;
    if (ws_size >= h_bytes + w2t_bytes) {
        unsigned short* h = (unsigned short*)d_ws;
        unsigned short* W2t = (unsigned short*)((char*)d_ws + h_bytes);
        prep_k<<<8000 + ROWS, 256, 0, stream>>>(toks, W1, b1, W2, h, W2t);
        hipError_t e = hipFuncSetAttribute(reinterpret_cast<const void*>(gemm8_k),
                                           hipFuncAttributeMaxDynamicSharedMemorySize, LDS_TOTAL);
        if (e == hipSuccess) {
            gemm8_k<<<(ROWS / 512) * (VOCAB / BN), 512, LDS_TOTAL, stream>>>(h, W2t, b2, out);
        } else {
            gemm_k<<<dim3(ROWS / 128, VOCAB / 128), 256, 0, stream>>>(h, W2t, b2, out);
        }
    } else {
        naive_k<<<ROWS / 8, 256, 0, stream>>>(toks, W1, b1, W2, b2, out);
    }
}

// Round 8
// 191.223 us; speedup vs baseline: 2.4107x; 2.4107x over previous
//
#include <hip/hip_runtime.h>
#include <hip/hip_bf16.h>

#define VOCAB 32000
#define EMBED 1024
#define SEQ 256
#define BATCH 8
#define ROWS (SEQ * BATCH) /* 2048 */

#define BM 256
#define BN 256
#define BK 64
#define NT (EMBED / BK) /* 16 K-tiles */

typedef short short8 __attribute__((ext_vector_type(8)));
typedef float f32x4 __attribute__((ext_vector_type(4)));
typedef float f32x16 __attribute__((ext_vector_type(16)));

__device__ __forceinline__ unsigned short f2bf(float f) {
    __hip_bfloat16 h = __float2bfloat16(f);
    return *reinterpret_cast<unsigned short*>(&h);
}

#define GLOAD_LDS16(gsrc, ldst)                                                        \
    __builtin_amdgcn_global_load_lds((const __attribute__((address_space(1))) void*)(gsrc), \
                                     (__attribute__((address_space(3))) void*)(ldst), 16, 0, 0)

// ---------------- fused pre-pass: transpose (blocks 0..7999) + embed (blocks 8000..10047) ----------------
__global__ __launch_bounds__(256) void prep_k(const int* __restrict__ toks,
                                              const float* __restrict__ W1,
                                              const float* __restrict__ b1,
                                              const float* __restrict__ W2,
                                              unsigned short* __restrict__ h,
                                              unsigned short* __restrict__ W2t) {
    __shared__ float tile[64][65];
    int bid = blockIdx.x;
    int t = threadIdx.x;
    if (bid < 8000) {
        int n0 = (bid % 500) * 64;
        int k0 = (bid / 500) * 64;
        int tx = t & 15, ty = t >> 4;
#pragma unroll
        for (int p = 0; p < 4; ++p) {
            int k = ty + p * 16;
            float4 v = *(const float4*)(W2 + (size_t)(k0 + k) * VOCAB + n0 + tx * 4);
            tile[k][tx * 4 + 0] = v.x; tile[k][tx * 4 + 1] = v.y;
            tile[k][tx * 4 + 2] = v.z; tile[k][tx * 4 + 3] = v.w;
        }
        __syncthreads();
        int kx = t & 15, ny = t >> 4;
#pragma unroll
        for (int p = 0; p < 4; ++p) {
            int n = ny + p * 16;
            int k = kx * 4;
            union { unsigned short u[4]; uint2 v; } o;
            o.u[0] = f2bf(tile[k + 0][n]); o.u[1] = f2bf(tile[k + 1][n]);
            o.u[2] = f2bf(tile[k + 2][n]); o.u[3] = f2bf(tile[k + 3][n]);
            *(uint2*)(W2t + (size_t)(n0 + n) * EMBED + k0 + k) = o.v;
        }
    } else {
        int r = bid - 8000;
        int s = r >> 3, b = r & 7;
        int t0 = (s >= 3) ? toks[(s - 3) * BATCH + b] : 0;
        int t1 = (s >= 2) ? toks[(s - 2) * BATCH + b] : 0;
        int t2 = (s >= 1) ? toks[(s - 1) * BATCH + b] : 0;
        int e = t * 4;
        float4 vb = *(const float4*)(b1 + e);
        float4 v0 = *(const float4*)(W1 + ((size_t)0 * VOCAB + t0) * EMBED + e);
        float4 v1 = *(const float4*)(W1 + ((size_t)1 * VOCAB + t1) * EMBED + e);
        float4 v2 = *(const float4*)(W1 + ((size_t)2 * VOCAB + t2) * EMBED + e);
        float x0 = fmaxf(vb.x + v0.x + v1.x + v2.x, 0.0f);
        float x1 = fmaxf(vb.y + v0.y + v1.y + v2.y, 0.0f);
        float x2 = fmaxf(vb.z + v0.z + v1.z + v2.z, 0.0f);
        float x3 = fmaxf(vb.w + v0.w + v1.w + v2.w, 0.0f);
        union { unsigned short u[4]; uint2 v; } o;
        o.u[0] = f2bf(x0); o.u[1] = f2bf(x1); o.u[2] = f2bf(x2); o.u[3] = f2bf(x3);
        *(uint2*)(h + (size_t)r * EMBED + e) = o.v;
    }
}

// ---------------- persistent 256x256 8-phase bf16 MFMA GEMM: 2 m-tiles per block ----------------
// EXACT r5 skeleton (178 us checkpoint): NT full-line epilogue via LDS transpose (T aliases
// buf1.A, safe: only buf0.A is boundary-prestaged), prestage-2, vmcnt(32), 128 KiB LDS,
// mg-inner XCD map. ONE change: MFMA shape 16x16x32 -> 32x32x16 (4061 vs 3378 FLOP/cyc,
// m119). Same LDS layout/swizzle (reads remain 16B-granule aligned), same staging, same
// phase/wait skeleton. Per phase: ldA = 4 ds_read_b128 (1 m-frag x 4 k-steps), ldB = 8
// (2 n-frags x 4 k-steps), 8 MFMA. acc = f32x16[4][2] = 128 VGPR (unchanged budget).
__global__ __launch_bounds__(512, 2) void gemm8_k(const unsigned short* __restrict__ A,
                                                  const unsigned short* __restrict__ B,
                                                  const float* __restrict__ b2,
                                                  float* __restrict__ out) {
    extern __shared__ char lds[];
    char* Al = lds;
    char* Bl = lds + 65536;

    // bijective XCD swizzle for 500 blocks (m204): q=62, r=4
    int wg = blockIdx.x;
    int xcd = wg & 7, idx = wg >> 3;
    int wgid = (xcd < 4 ? xcd * 63 : 4 * 63 + (xcd - 4) * 62) + idx;
    int mg = wgid & 3;            // m fast: same-stripe blocks adjacent
    int n0 = (wgid >> 2) * BN;
    int m0 = mg * 512;

    int tid = threadIdx.x;
    int w = tid >> 6, lane = tid & 63;
    int wm = w >> 2, wn = w & 3;
    int ksw = ((lane & 7) ^ ((lane >> 3) & 7)) * 8;

    f32x16 acc[4][2] = {};
    short8 af[4], bfr[2][4];

    auto stage = [&](const unsigned short* __restrict__ g, int grow0, char* ldsbase, int t) {
#pragma unroll
        for (int j = 0; j < 2; ++j) {
            int c = j * 8 + w;
            int row = c * 8 + (lane >> 3);
            const unsigned short* src = g + (size_t)(grow0 + row) * EMBED + t * BK + ksw;
            GLOAD_LDS16(src, ldsbase + c * 1024);
        }
    };
    auto stA = [&](int buf, int hh, int t, int mbase) { stage(A, mbase + hh * 128, Al + buf * 32768 + hh * 16384, t); };
    auto stB = [&](int buf, int hh, int t) { stage(B, n0 + hh * 128, Bl + buf * 32768 + hh * 16384, t); };

    // ---- register loads (swizzled ds_read_b128), 32x32x16 fragments ----
    // A-frag: row = lane&31, k = ks*16 + (lane>>5)*8 + e  (16B granule-aligned)
    auto ldA = [&](int buf, int qq) {
#pragma unroll
        for (int ks = 0; ks < 4; ++ks) {
            int row = wm * 128 + qq * 32 + (lane & 31);
            int cb = (ks * 32 + ((lane >> 5) << 4)) ^ ((row & 7) << 4);
            af[ks] = *(const short8*)(Al + buf * 32768 + row * 128 + cb);
        }
    };
    auto ldB = [&](int buf) {
#pragma unroll
        for (int nf = 0; nf < 2; ++nf)
#pragma unroll
            for (int ks = 0; ks < 4; ++ks) {
                int row = wn * 64 + nf * 32 + (lane & 31);
                int cb = (ks * 32 + ((lane >> 5) << 4)) ^ ((row & 7) << 4);
                bfr[nf][ks] = *(const short8*)(Bl + buf * 32768 + row * 128 + cb);
            }
    };

#define MFMA_Q(q)                                                                             \
    __builtin_amdgcn_s_setprio(1);                                                            \
    _Pragma("unroll") for (int ks = 0; ks < 4; ++ks)                                          \
        _Pragma("unroll") for (int nf = 0; nf < 2; ++nf)                                      \
            acc[(q)][nf] = __builtin_amdgcn_mfma_f32_32x32x16_bf16(                           \
                af[ks], bfr[nf][ks], acc[(q)][nf], 0, 0, 0);                                  \
    __builtin_amdgcn_s_setprio(0);

#define PH(ldbuf, q, DO_LDB, STAGE_STMT, WAITV)                                               \
    ldA(ldbuf, q);                                                                            \
    if (DO_LDB) ldB(ldbuf);                                                                   \
    STAGE_STMT;                                                                               \
    if (DO_LDB) asm volatile("s_waitcnt lgkmcnt(8)");                                         \
    if (WAITV) asm volatile("s_waitcnt vmcnt(4)");                                            \
    __builtin_amdgcn_s_barrier();                                                             \
    asm volatile("s_waitcnt lgkmcnt(0)");                                                     \
    MFMA_Q(q);                                                                                \
    __builtin_amdgcn_s_barrier();

    auto kloop = [&](int mcur) {
        for (int it = 0; it < NT / 2; ++it) {
            int t1 = (it * 2 + 1) & (NT - 1);
            int t2 = (it * 2 + 2) & (NT - 1);
            int t3 = (it * 2 + 3) & (NT - 1);
            PH(0, 0, true,  stA(1, 0, t1, mcur), false)
            PH(0, 1, false, stA(1, 1, t1, mcur), false)
            PH(0, 2, false, stB(0, 0, t2),       false)
            PH(0, 3, false, stB(0, 1, t2),       true)
            PH(1, 0, true,  stA(0, 0, t2, mcur), false)
            PH(1, 1, false, stA(0, 1, t2, mcur), false)
            PH(1, 2, false, stB(1, 0, t3),       false)
            PH(1, 3, false, stB(1, 1, t3),       true)
        }
    };

    // ---- full-line NT epilogue via LDS transpose (dead buf1.A region, 32 KB) ----
    // Pass p (0..7): rows mbase+p*32..+31; wave wm==p>>2 dumps m-frag mf=p&3.
    // 32x32 C/D layout: col = lane&31, row_in_frag = (reg&3) + 8*(reg>>2) + 4*(lane>>5).
    auto epi = [&](int mbase) {
        char* T = Al + 32768;
        float bias[2];
#pragma unroll
        for (int nf = 0; nf < 2; ++nf) bias[nf] = b2[n0 + wn * 64 + nf * 32 + (lane & 31)];
#pragma unroll
        for (int p = 0; p < 8; ++p) {
            __builtin_amdgcn_s_barrier();   // prior pass readback done before overwrite
            if (wm == (p >> 2)) {
                int mf = p & 3;
#pragma unroll
                for (int nf = 0; nf < 2; ++nf) {
                    int c = wn * 64 + nf * 32 + (lane & 31);
#pragma unroll
                    for (int reg = 0; reg < 16; ++reg) {
                        int rl = (reg & 3) + 8 * (reg >> 2) + 4 * (lane >> 5);
                        *(float*)(T + rl * 1024 + c * 4) = acc[mf][nf][reg] + bias[nf];
                    }
                }
            }
            __builtin_amdgcn_s_barrier();
#pragma unroll
            for (int rr = 0; rr < 4; ++rr) {
                int rl = w * 4 + rr;
                f32x4 v = *(const f32x4*)(T + rl * 1024 + lane * 16);
                int grow = mbase + p * 32 + rl;
                __builtin_nontemporal_store(v, (f32x4*)(out + (size_t)grow * VOCAB + n0 + lane * 4));
            }
        }
    };

    // ---- prologue (m-tile 0) ----
    stA(0, 0, 0, m0); stA(0, 1, 0, m0); stB(0, 0, 0); stB(0, 1, 0);
    stB(1, 0, 1); stB(1, 1, 1);
    asm volatile("s_waitcnt vmcnt(4)");
    __builtin_amdgcn_s_barrier();

    kloop(m0);

    // ---- boundary (r5 semantics): wrap prefetch left buf0.B=B(t0), buf1.B=B(t1).
    // Prestage ONLY buf0.A with A(m1,t0) before the epilogue (T aliases buf1.A);
    // kloop(m1) ph1-2 restage buf1.A normally. vmcnt(32) + barrier before reuse.
    int m1 = m0 + 256;
    stA(0, 0, 0, m1); stA(0, 1, 0, m1);
    epi(m0);
    asm volatile("s_waitcnt vmcnt(32)" ::: "memory");
    __builtin_amdgcn_s_barrier();

#pragma unroll
    for (int mf = 0; mf < 4; ++mf)
#pragma unroll
        for (int nf = 0; nf < 2; ++nf)
#pragma unroll
            for (int e = 0; e < 16; ++e)
                acc[mf][nf][e] = 0.f;

    kloop(m1);
    epi(m1);
#undef PH
#undef MFMA_Q
}

// ---------------- fallback 128^2 2-phase GEMM (if 128 KiB dyn LDS unavailable) ----------------
__global__ __launch_bounds__(256) void gemm_k(const unsigned short* __restrict__ h,
                                              const unsigned short* __restrict__ W2t,
                                              const float* __restrict__ b2,
                                              float* __restrict__ out) {
    __shared__ unsigned short Alds[128 * 64];
    __shared__ unsigned short Blds[128 * 64];
    int m0 = blockIdx.x * 128;
    int n0 = blockIdx.y * 128;
    int tid = threadIdx.x;
    int wave = tid >> 6, lane = tid & 63;
    int wr = (wave >> 1) * 64;
    int wc = (wave & 1) * 64;
    int lrow = lane & 15;
    int khalf = (lane >> 4) * 8;
    f32x4 acc[4][4] = {};
    for (int kt = 0; kt < EMBED; kt += 64) {
#pragma unroll
        for (int i = 0; i < 4; ++i) {
            int base = (wave * 4 + i) * 1024;
            int lin = base + lane * 16;
            int row = lin >> 7;
            int colu = (lin & 127) >> 1;
            GLOAD_LDS16(h + (size_t)(m0 + row) * EMBED + kt + colu, (char*)Alds + base);
            GLOAD_LDS16(W2t + (size_t)(n0 + row) * EMBED + kt + colu, (char*)Blds + base);
        }
        __syncthreads();
#pragma unroll
        for (int kc = 0; kc < 2; ++kc) {
            short8 af[4], bf[4];
#pragma unroll
            for (int m = 0; m < 4; ++m)
                af[m] = *(const short8*)(Alds + (wr + m * 16 + lrow) * 64 + kc * 32 + khalf);
#pragma unroll
            for (int n = 0; n < 4; ++n)
                bf[n] = *(const short8*)(Blds + (wc + n * 16 + lrow) * 64 + kc * 32 + khalf);
#pragma unroll
            for (int m = 0; m < 4; ++m)
#pragma unroll
                for (int n = 0; n < 4; ++n)
                    acc[m][n] = __builtin_amdgcn_mfma_f32_16x16x32_bf16(af[m], bf[n], acc[m][n], 0, 0, 0);
        }
        __syncthreads();
    }
    int colq = lane & 15;
    int rowq = (lane >> 4) * 4;
#pragma unroll
    for (int m = 0; m < 4; ++m)
#pragma unroll
        for (int n = 0; n < 4; ++n) {
            int col = n0 + wc + n * 16 + colq;
            float bias = b2[col];
#pragma unroll
            for (int q = 0; q < 4; ++q)
                out[(size_t)(m0 + wr + m * 16 + rowq + q) * VOCAB + col] = acc[m][n][q] + bias;
        }
}

// ---------------- fallback (ws too small): correct fp32 path ----------------
__global__ __launch_bounds__(256) void naive_k(const int* __restrict__ toks,
                                               const float* __restrict__ W1,
                                               const float* __restrict__ b1,
                                               const float* __restrict__ W2,
                                               const float* __restrict__ b2,
                                               float* __restrict__ out) {
    __shared__ float hs[8][1024];
    int r0 = blockIdx.x * 8;
    int e = threadIdx.x * 4;
    for (int rr = 0; rr < 8; ++rr) {
        int r = r0 + rr, s = r >> 3, b = r & 7;
        int t0 = (s >= 3) ? toks[(s - 3) * BATCH + b] : 0;
        int t1 = (s >= 2) ? toks[(s - 2) * BATCH + b] : 0;
        int t2 = (s >= 1) ? toks[(s - 1) * BATCH + b] : 0;
        float4 vb = *(const float4*)(b1 + e);
        float4 v0 = *(const float4*)(W1 + ((size_t)t0) * EMBED + e);
        float4 v1 = *(const float4*)(W1 + ((size_t)VOCAB + t1) * EMBED + e);
        float4 v2 = *(const float4*)(W1 + ((size_t)2 * VOCAB + t2) * EMBED + e);
        hs[rr][e + 0] = fmaxf(vb.x + v0.x + v1.x + v2.x, 0.0f);
        hs[rr][e + 1] = fmaxf(vb.y + v0.y + v1.y + v2.y, 0.0f);
        hs[rr][e + 2] = fmaxf(vb.z + v0.z + v1.z + v2.z, 0.0f);
        hs[rr][e + 3] = fmaxf(vb.w + v0.w + v1.w + v2.w, 0.0f);
    }
    __syncthreads();
    for (int v = threadIdx.x; v < VOCAB; v += 256) {
        float acc[8];
#pragma unroll
        for (int i = 0; i < 8; ++i) acc[i] = b2[v];
        for (int ee = 0; ee < EMBED; ++ee) {
            float wv = W2[(size_t)ee * VOCAB + v];
#pragma unroll
            for (int i = 0; i < 8; ++i) acc[i] += hs[i][ee] * wv;
        }
#pragma unroll
        for (int i = 0; i < 8; ++i) out[(size_t)(r0 + i) * VOCAB + v] = acc[i];
    }
}

extern "C" void kernel_launch(void* const* d_in, const int* in_sizes, int n_in,
                              void* d_out, int out_size, void* d_ws, size_t ws_size,
                              hipStream_t stream) {
    const int* toks = (const int*)d_in[0];
    const float* W1 = (const float*)d_in[1];
    const float* b1 = (const float*)d_in[2];
    const float* W2 = (const float*)d_in[3];
    const float* b2 = (const float*)d_in[4];
    float* out = (float*)d_out;

    const size_t h_bytes = (size_t)ROWS * EMBED * 2;
    const size_t w2t_bytes = (size_t)VOCAB * EMBED * 2;
    if (ws_size >= h_bytes + w2t_bytes) {
        unsigned short* h = (unsigned short*)d_ws;
        unsigned short* W2t = (unsigned short*)((char*)d_ws + h_bytes);
        prep_k<<<8000 + ROWS, 256, 0, stream>>>(toks, W1, b1, W2, h, W2t);
        hipError_t e = hipFuncSetAttribute(reinterpret_cast<const void*>(gemm8_k),
                                           hipFuncAttributeMaxDynamicSharedMemorySize, 131072);
        if (e == hipSuccess) {
            gemm8_k<<<(ROWS / 512) * (VOCAB / BN), 512, 131072, stream>>>(h, W2t, b2, out);
        } else {
            gemm_k<<<dim3(ROWS / 128, VOCAB / 128), 256, 0, stream>>>(h, W2t, b2, out);
        }
    } else {
        naive_k<<<ROWS / 8, 256, 0, stream>>>(toks, W1, b1, W2, b2, out);
    }
}

// Round 9
// 175.161 us; speedup vs baseline: 2.6318x; 1.0917x over previous
//
#include <hip/hip_runtime.h>
#include <hip/hip_bf16.h>

#define VOCAB 32000
#define EMBED 1024
#define SEQ 256
#define BATCH 8
#define ROWS (SEQ * BATCH) /* 2048 */

#define BM 256
#define BN 256
#define BK 64
#define NT (EMBED / BK) /* 16 K-tiles */

typedef short short8 __attribute__((ext_vector_type(8)));
typedef float f32x4 __attribute__((ext_vector_type(4)));

__device__ __forceinline__ unsigned short f2bf(float f) {
    __hip_bfloat16 h = __float2bfloat16(f);
    return *reinterpret_cast<unsigned short*>(&h);
}

#define GLOAD_LDS16(gsrc, ldst)                                                        \
    __builtin_amdgcn_global_load_lds((const __attribute__((address_space(1))) void*)(gsrc), \
                                     (__attribute__((address_space(3))) void*)(ldst), 16, 0, 0)

// ---------------- fused pre-pass: transpose (blocks 0..7999) + embed (blocks 8000..10047) ----------------
__global__ __launch_bounds__(256) void prep_k(const int* __restrict__ toks,
                                              const float* __restrict__ W1,
                                              const float* __restrict__ b1,
                                              const float* __restrict__ W2,
                                              unsigned short* __restrict__ h,
                                              unsigned short* __restrict__ W2t) {
    __shared__ float tile[64][65];
    int bid = blockIdx.x;
    int t = threadIdx.x;
    if (bid < 8000) {
        int n0 = (bid % 500) * 64;
        int k0 = (bid / 500) * 64;
        int tx = t & 15, ty = t >> 4;
#pragma unroll
        for (int p = 0; p < 4; ++p) {
            int k = ty + p * 16;
            float4 v = *(const float4*)(W2 + (size_t)(k0 + k) * VOCAB + n0 + tx * 4);
            tile[k][tx * 4 + 0] = v.x; tile[k][tx * 4 + 1] = v.y;
            tile[k][tx * 4 + 2] = v.z; tile[k][tx * 4 + 3] = v.w;
        }
        __syncthreads();
        int kx = t & 15, ny = t >> 4;
#pragma unroll
        for (int p = 0; p < 4; ++p) {
            int n = ny + p * 16;
            int k = kx * 4;
            union { unsigned short u[4]; uint2 v; } o;
            o.u[0] = f2bf(tile[k + 0][n]); o.u[1] = f2bf(tile[k + 1][n]);
            o.u[2] = f2bf(tile[k + 2][n]); o.u[3] = f2bf(tile[k + 3][n]);
            *(uint2*)(W2t + (size_t)(n0 + n) * EMBED + k0 + k) = o.v;
        }
    } else {
        int r = bid - 8000;
        int s = r >> 3, b = r & 7;
        int t0 = (s >= 3) ? toks[(s - 3) * BATCH + b] : 0;
        int t1 = (s >= 2) ? toks[(s - 2) * BATCH + b] : 0;
        int t2 = (s >= 1) ? toks[(s - 1) * BATCH + b] : 0;
        int e = t * 4;
        float4 vb = *(const float4*)(b1 + e);
        float4 v0 = *(const float4*)(W1 + ((size_t)0 * VOCAB + t0) * EMBED + e);
        float4 v1 = *(const float4*)(W1 + ((size_t)1 * VOCAB + t1) * EMBED + e);
        float4 v2 = *(const float4*)(W1 + ((size_t)2 * VOCAB + t2) * EMBED + e);
        float x0 = fmaxf(vb.x + v0.x + v1.x + v2.x, 0.0f);
        float x1 = fmaxf(vb.y + v0.y + v1.y + v2.y, 0.0f);
        float x2 = fmaxf(vb.z + v0.z + v1.z + v2.z, 0.0f);
        float x3 = fmaxf(vb.w + v0.w + v1.w + v2.w, 0.0f);
        union { unsigned short u[4]; uint2 v; } o;
        o.u[0] = f2bf(x0); o.u[1] = f2bf(x1); o.u[2] = f2bf(x2); o.u[3] = f2bf(x3);
        *(uint2*)(h + (size_t)r * EMBED + e) = o.v;
    }
}

// ---------------- persistent 256x256 8-phase bf16 MFMA GEMM: 4 m-tiles per block ----------------
// EXACT r5 skeleton (178 us checkpoint: 16x16x32 MFMA, NT full-line epilogue via LDS
// transpose with T aliasing buf1.A [safe: boundary prestages ONLY buf0.A], prestage-2,
// vmcnt(32), 128 KiB LDS). ONE change: 250 blocks x 4 m-tiles (single block generation;
// every inter-m-tile transition uses the bubble-free boundary instead of a full block
// swap with store-drain + cold prologue).
__global__ __launch_bounds__(512, 2) void gemm8_k(const unsigned short* __restrict__ A,
                                                  const unsigned short* __restrict__ B,
                                                  const float* __restrict__ b2,
                                                  float* __restrict__ out) {
    extern __shared__ char lds[];
    char* Al = lds;
    char* Bl = lds + 65536;

    // bijective XCD swizzle for 250 blocks (m204): q=31, r=2
    int wg = blockIdx.x;
    int xcd = wg & 7, idx = wg >> 3;
    int wgid = (xcd < 2 ? xcd * 32 : 2 * 32 + (xcd - 2) * 31) + idx;
    int mg = wgid & 1;            // m fast: stripe-sharing blocks adjacent
    int n0 = (wgid >> 1) * BN;    // 125 n-stripes
    int ms = mg * 1024;           // this block covers ms + {0,256,512,768}

    int tid = threadIdx.x;
    int w = tid >> 6, lane = tid & 63;
    int wm = w >> 2, wn = w & 3;
    int ksw = ((lane & 7) ^ ((lane >> 3) & 7)) * 8;

    f32x4 acc[8][4] = {};
    short8 af[2][2], bfr[4][2];

    auto stage = [&](const unsigned short* __restrict__ g, int grow0, char* ldsbase, int t) {
#pragma unroll
        for (int j = 0; j < 2; ++j) {
            int c = j * 8 + w;
            int row = c * 8 + (lane >> 3);
            const unsigned short* src = g + (size_t)(grow0 + row) * EMBED + t * BK + ksw;
            GLOAD_LDS16(src, ldsbase + c * 1024);
        }
    };
    auto stA = [&](int buf, int hh, int t, int mbase) { stage(A, mbase + hh * 128, Al + buf * 32768 + hh * 16384, t); };
    auto stB = [&](int buf, int hh, int t) { stage(B, n0 + hh * 128, Bl + buf * 32768 + hh * 16384, t); };

    auto ldA = [&](int buf, int qq) {
#pragma unroll
        for (int i = 0; i < 2; ++i)
#pragma unroll
            for (int kk = 0; kk < 2; ++kk) {
                int row = wm * 128 + (qq * 2 + i) * 16 + (lane & 15);
                int cb = ((lane >> 4) * 16 + kk * 64) ^ ((lane & 7) << 4);
                af[i][kk] = *(const short8*)(Al + buf * 32768 + row * 128 + cb);
            }
    };
    auto ldB = [&](int buf) {
#pragma unroll
        for (int n = 0; n < 4; ++n)
#pragma unroll
            for (int kk = 0; kk < 2; ++kk) {
                int row = wn * 64 + n * 16 + (lane & 15);
                int cb = ((lane >> 4) * 16 + kk * 64) ^ ((lane & 7) << 4);
                bfr[n][kk] = *(const short8*)(Bl + buf * 32768 + row * 128 + cb);
            }
    };

#define MFMA_Q(q)                                                                             \
    __builtin_amdgcn_s_setprio(1);                                                            \
    _Pragma("unroll") for (int i = 0; i < 2; ++i)                                             \
        _Pragma("unroll") for (int n = 0; n < 4; ++n)                                         \
            _Pragma("unroll") for (int kk = 0; kk < 2; ++kk)                                  \
                acc[(q)*2 + i][n] = __builtin_amdgcn_mfma_f32_16x16x32_bf16(                  \
                    af[i][kk], bfr[n][kk], acc[(q)*2 + i][n], 0, 0, 0);                       \
    __builtin_amdgcn_s_setprio(0);

#define PH(ldbuf, q, DO_LDB, STAGE_STMT, WAITV)                                               \
    ldA(ldbuf, q);                                                                            \
    if (DO_LDB) ldB(ldbuf);                                                                   \
    STAGE_STMT;                                                                               \
    if (DO_LDB) asm volatile("s_waitcnt lgkmcnt(8)");                                         \
    if (WAITV) asm volatile("s_waitcnt vmcnt(4)");                                            \
    __builtin_amdgcn_s_barrier();                                                             \
    asm volatile("s_waitcnt lgkmcnt(0)");                                                     \
    MFMA_Q(q);                                                                                \
    __builtin_amdgcn_s_barrier();

    auto kloop = [&](int mcur) {
        for (int it = 0; it < NT / 2; ++it) {
            int t1 = (it * 2 + 1) & (NT - 1);
            int t2 = (it * 2 + 2) & (NT - 1);
            int t3 = (it * 2 + 3) & (NT - 1);
            PH(0, 0, true,  stA(1, 0, t1, mcur), false)
            PH(0, 1, false, stA(1, 1, t1, mcur), false)
            PH(0, 2, false, stB(0, 0, t2),       false)
            PH(0, 3, false, stB(0, 1, t2),       true)
            PH(1, 0, true,  stA(0, 0, t2, mcur), false)
            PH(1, 1, false, stA(0, 1, t2, mcur), false)
            PH(1, 2, false, stB(1, 0, t3),       false)
            PH(1, 3, false, stB(1, 1, t3),       true)
        }
    };

    // ---- full-line NT epilogue via LDS transpose (dead buf1.A region, 32 KB) ----
    int colq = lane & 15;
    int rowq4 = (lane >> 4) * 4;
    auto epi = [&](int mbase) {
        char* T = Al + 32768;
        float bias[4];
#pragma unroll
        for (int nf = 0; nf < 4; ++nf) bias[nf] = b2[n0 + wn * 64 + nf * 16 + colq];
#pragma unroll
        for (int p = 0; p < 8; ++p) {
            __builtin_amdgcn_s_barrier();   // prior pass readback done before overwrite
            if (wm == (p >> 2)) {
#pragma unroll
                for (int mi = 0; mi < 2; ++mi) {
                    int mf = (p & 3) * 2 + mi;
                    int rl = mi * 16 + rowq4;
#pragma unroll
                    for (int nf = 0; nf < 4; ++nf) {
                        int c = wn * 64 + nf * 16 + colq;
#pragma unroll
                        for (int q = 0; q < 4; ++q)
                            *(float*)(T + (rl + q) * 1024 + c * 4) = acc[mf][nf][q] + bias[nf];
                    }
                }
            }
            __builtin_amdgcn_s_barrier();
#pragma unroll
            for (int rr = 0; rr < 4; ++rr) {
                int rl = w * 4 + rr;
                f32x4 v = *(const f32x4*)(T + rl * 1024 + lane * 16);
                int grow = mbase + p * 32 + rl;
                __builtin_nontemporal_store(v, (f32x4*)(out + (size_t)grow * VOCAB + n0 + lane * 4));
            }
        }
    };

    // ---- prologue (m-tile 0) ----
    stA(0, 0, 0, ms); stA(0, 1, 0, ms); stB(0, 0, 0); stB(0, 1, 0);
    stB(1, 0, 1); stB(1, 1, 1);
    asm volatile("s_waitcnt vmcnt(4)");
    __builtin_amdgcn_s_barrier();

    kloop(ms);

    // ---- 3 bubble-free boundaries (r5 semantics each): wrap prefetch left
    // buf0.B=B(t0), buf1.B=B(t1). Prestage ONLY buf0.A with A(next,t0) before the
    // epilogue (T aliases buf1.A); kloop(next) ph1-2 restage buf1.A normally.
    // FIFO at vmcnt(32): 4 wrapB + 4 prestageA + 4 bias + 32 stores = 44 outstanding
    // -> retires the 12 loads, stores untouched.
#pragma unroll 1
    for (int mt = 1; mt < 4; ++mt) {
        int mn = ms + mt * 256;
        stA(0, 0, 0, mn); stA(0, 1, 0, mn);
        epi(mn - 256);
        asm volatile("s_waitcnt vmcnt(32)" ::: "memory");
        __builtin_amdgcn_s_barrier();
#pragma unroll
        for (int mf = 0; mf < 8; ++mf)
#pragma unroll
            for (int nf = 0; nf < 4; ++nf)
                acc[mf][nf] = f32x4{0.f, 0.f, 0.f, 0.f};
        kloop(mn);
    }
    epi(ms + 768);
#undef PH
#undef MFMA_Q
}

// ---------------- fallback 128^2 2-phase GEMM (if 128 KiB dyn LDS unavailable) ----------------
__global__ __launch_bounds__(256) void gemm_k(const unsigned short* __restrict__ h,
                                              const unsigned short* __restrict__ W2t,
                                              const float* __restrict__ b2,
                                              float* __restrict__ out) {
    __shared__ unsigned short Alds[128 * 64];
    __shared__ unsigned short Blds[128 * 64];
    int m0 = blockIdx.x * 128;
    int n0 = blockIdx.y * 128;
    int tid = threadIdx.x;
    int wave = tid >> 6, lane = tid & 63;
    int wr = (wave >> 1) * 64;
    int wc = (wave & 1) * 64;
    int lrow = lane & 15;
    int khalf = (lane >> 4) * 8;
    f32x4 acc[4][4] = {};
    for (int kt = 0; kt < EMBED; kt += 64) {
#pragma unroll
        for (int i = 0; i < 4; ++i) {
            int base = (wave * 4 + i) * 1024;
            int lin = base + lane * 16;
            int row = lin >> 7;
            int colu = (lin & 127) >> 1;
            GLOAD_LDS16(h + (size_t)(m0 + row) * EMBED + kt + colu, (char*)Alds + base);
            GLOAD_LDS16(W2t + (size_t)(n0 + row) * EMBED + kt + colu, (char*)Blds + base);
        }
        __syncthreads();
#pragma unroll
        for (int kc = 0; kc < 2; ++kc) {
            short8 af[4], bf[4];
#pragma unroll
            for (int m = 0; m < 4; ++m)
                af[m] = *(const short8*)(Alds + (wr + m * 16 + lrow) * 64 + kc * 32 + khalf);
#pragma unroll
            for (int n = 0; n < 4; ++n)
                bf[n] = *(const short8*)(Blds + (wc + n * 16 + lrow) * 64 + kc * 32 + khalf);
#pragma unroll
            for (int m = 0; m < 4; ++m)
#pragma unroll
                for (int n = 0; n < 4; ++n)
                    acc[m][n] = __builtin_amdgcn_mfma_f32_16x16x32_bf16(af[m], bf[n], acc[m][n], 0, 0, 0);
        }
        __syncthreads();
    }
    int colq = lane & 15;
    int rowq = (lane >> 4) * 4;
#pragma unroll
    for (int m = 0; m < 4; ++m)
#pragma unroll
        for (int n = 0; n < 4; ++n) {
            int col = n0 + wc + n * 16 + colq;
            float bias = b2[col];
#pragma unroll
            for (int q = 0; q < 4; ++q)
                out[(size_t)(m0 + wr + m * 16 + rowq + q) * VOCAB + col] = acc[m][n][q] + bias;
        }
}

// ---------------- fallback (ws too small): correct fp32 path ----------------
__global__ __launch_bounds__(256) void naive_k(const int* __restrict__ toks,
                                               const float* __restrict__ W1,
                                               const float* __restrict__ b1,
                                               const float* __restrict__ W2,
                                               const float* __restrict__ b2,
                                               float* __restrict__ out) {
    __shared__ float hs[8][1024];
    int r0 = blockIdx.x * 8;
    int e = threadIdx.x * 4;
    for (int rr = 0; rr < 8; ++rr) {
        int r = r0 + rr, s = r >> 3, b = r & 7;
        int t0 = (s >= 3) ? toks[(s - 3) * BATCH + b] : 0;
        int t1 = (s >= 2) ? toks[(s - 2) * BATCH + b] : 0;
        int t2 = (s >= 1) ? toks[(s - 1) * BATCH + b] : 0;
        float4 vb = *(const float4*)(b1 + e);
        float4 v0 = *(const float4*)(W1 + ((size_t)t0) * EMBED + e);
        float4 v1 = *(const float4*)(W1 + ((size_t)VOCAB + t1) * EMBED + e);
        float4 v2 = *(const float4*)(W1 + ((size_t)2 * VOCAB + t2) * EMBED + e);
        hs[rr][e + 0] = fmaxf(vb.x + v0.x + v1.x + v2.x, 0.0f);
        hs[rr][e + 1] = fmaxf(vb.y + v0.y + v1.y + v2.y, 0.0f);
        hs[rr][e + 2] = fmaxf(vb.z + v0.z + v1.z + v2.z, 0.0f);
        hs[rr][e + 3] = fmaxf(vb.w + v0.w + v1.w + v2.w, 0.0f);
    }
    __syncthreads();
    for (int v = threadIdx.x; v < VOCAB; v += 256) {
        float acc[8];
#pragma unroll
        for (int i = 0; i < 8; ++i) acc[i] = b2[v];
        for (int ee = 0; ee < EMBED; ++ee) {
            float wv = W2[(size_t)ee * VOCAB + v];
#pragma unroll
            for (int i = 0; i < 8; ++i) acc[i] += hs[i][ee] * wv;
        }
#pragma unroll
        for (int i = 0; i < 8; ++i) out[(size_t)(r0 + i) * VOCAB + v] = acc[i];
    }
}

extern "C" void kernel_launch(void* const* d_in, const int* in_sizes, int n_in,
                              void* d_out, int out_size, void* d_ws, size_t ws_size,
                              hipStream_t stream) {
    const int* toks = (const int*)d_in[0];
    const float* W1 = (const float*)d_in[1];
    const float* b1 = (const float*)d_in[2];
    const float* W2 = (const float*)d_in[3];
    const float* b2 = (const float*)d_in[4];
    float* out = (float*)d_out;

    const size_t h_bytes = (size_t)ROWS * EMBED * 2;
    const size_t w2t_bytes = (size_t)VOCAB * EMBED * 2;
    if (ws_size >= h_bytes + w2t_bytes) {
        unsigned short* h = (unsigned short*)d_ws;
        unsigned short* W2t = (unsigned short*)((char*)d_ws + h_bytes);
        prep_k<<<8000 + ROWS, 256, 0, stream>>>(toks, W1, b1, W2, h, W2t);
        hipError_t e = hipFuncSetAttribute(reinterpret_cast<const void*>(gemm8_k),
                                           hipFuncAttributeMaxDynamicSharedMemorySize, 131072);
        if (e == hipSuccess) {
            gemm8_k<<<(ROWS / 1024) * (VOCAB / BN), 512, 131072, stream>>>(h, W2t, b2, out);
        } else {
            gemm_k<<<dim3(ROWS / 128, VOCAB / 128), 256, 0, stream>>>(h, W2t, b2, out);
        }
    } else {
        naive_k<<<ROWS / 8, 256, 0, stream>>>(toks, W1, b1, W2, b2, out);
    }
}